// Round 1
// baseline (5598.640 us; speedup 1.0000x reference)
//
#include <hip/hip_runtime.h>
#include <hip/hip_bf16.h>

#define B_ 4
#define L_ 8192
#define D_ 1024
#define H_ 16
#define SCALE 0.125f

__device__ __forceinline__ float blo(unsigned v) { return __uint_as_float(v << 16); }
__device__ __forceinline__ float bhi(unsigned v) { return __uint_as_float(v & 0xffff0000u); }

// ---- xmean[b][j] = mean over l of x[b][l][j] (partial chunks + atomic) ----
__global__ __launch_bounds__(256) void xmean_kernel(const float* __restrict__ x,
                                                    float* __restrict__ xmean) {
    int c = blockIdx.x;                 // l-chunk (32 chunks of 256)
    int j = blockIdx.y * 256 + threadIdx.x;
    int b = blockIdx.z;
    const float* xp = x + ((size_t)b * L_ + (size_t)c * 256) * D_ + j;
    float s = 0.f;
    for (int l = 0; l < 256; ++l) s += xp[(size_t)l * D_];
    atomicAdd(&xmean[b * D_ + j], s * (1.0f / L_));
}

// ---- out[b][j] = dot(in[b], W[j]) + bias[j]   (4 rows, tiny) ----
__global__ __launch_bounds__(256) void vecmat_kernel(const float* __restrict__ in,
                                                     const float* __restrict__ W,
                                                     const float* __restrict__ bias,
                                                     float* __restrict__ out) {
    __shared__ float vs[D_];
    int b = blockIdx.y;
    int j = blockIdx.x * 256 + threadIdx.x;
    for (int t = threadIdx.x; t < D_; t += 256) vs[t] = in[b * D_ + t];
    __syncthreads();
    const float* wr = W + (size_t)j * D_;
    float acc = 0.f;
    #pragma unroll 4
    for (int k = 0; k < D_; k += 4) {
        float4 w4 = *(const float4*)(wr + k);
        acc += vs[k] * w4.x + vs[k + 1] * w4.y + vs[k + 2] * w4.z + vs[k + 3] * w4.w;
    }
    out[b * D_ + j] = acc + bias[j];
}

// ---- Ksamp[b][u][:] = x[b][idx_k[u]] @ Wk.T + bk   (fp32, selection-critical) ----
__global__ __launch_bounds__(256) void ksamp_kernel(const float* __restrict__ x,
                                                    const float* __restrict__ Wk,
                                                    const float* __restrict__ bk,
                                                    const int* __restrict__ idx_k,
                                                    float* __restrict__ Ksamp, int U) {
    __shared__ float vs[D_];
    int u = blockIdx.x, b = blockIdx.y;
    int row = idx_k[u];
    const float* xp = x + ((size_t)b * L_ + row) * D_;
    for (int t = threadIdx.x; t < D_; t += 256) vs[t] = xp[t];
    __syncthreads();
    #pragma unroll
    for (int r = 0; r < 4; ++r) {
        int j = r * 256 + threadIdx.x;
        const float* wr = Wk + (size_t)j * D_;
        float acc = 0.f;
        #pragma unroll 4
        for (int k = 0; k < D_; k += 4) {
            float4 w4 = *(const float4*)(wr + k);
            acc += vs[k] * w4.x + vs[k + 1] * w4.y + vs[k + 2] * w4.z + vs[k + 3] * w4.w;
        }
        Ksamp[((size_t)b * U + u) * D_ + j] = acc + bk[j];
    }
}

// ---- fused QKV projection: C[32768,3072] = x @ [Wq;Wk;Wv].T + bias ----
// Q stored fp32 (needed for fp32-exact M/top-k); K,V stored bf16.
__global__ __launch_bounds__(256) void qkv_gemm(const float* __restrict__ x,
        const float* __restrict__ Wq, const float* __restrict__ bq,
        const float* __restrict__ Wk, const float* __restrict__ bk,
        const float* __restrict__ Wv, const float* __restrict__ bv,
        float* __restrict__ Q, __hip_bfloat16* __restrict__ Kb,
        __hip_bfloat16* __restrict__ Vb) {
    __shared__ float As[32][132];
    __shared__ float Bs[32][132];
    const int tid = threadIdx.x;
    const int m0 = blockIdx.y * 128;
    const int n0 = blockIdx.x * 128;

    const float* W; const float* bias; int which; int nb;
    if (n0 < 1024)      { W = Wq; bias = bq; which = 0; nb = n0; }
    else if (n0 < 2048) { W = Wk; bias = bk; which = 1; nb = n0 - 1024; }
    else                { W = Wv; bias = bv; which = 2; nb = n0 - 2048; }

    const int tm = tid & 15, tn = tid >> 4;
    const int lr = tid >> 3;            // 0..31
    const int lc = (tid & 7) * 4;       // 0,4,..,28

    float acc[8][8];
    #pragma unroll
    for (int i = 0; i < 8; ++i)
        #pragma unroll
        for (int j = 0; j < 8; ++j) acc[i][j] = 0.f;

    for (int kt = 0; kt < 1024; kt += 32) {
        __syncthreads();
        #pragma unroll
        for (int i = 0; i < 4; ++i) {
            int r = lr + i * 32;
            float4 a4 = *(const float4*)(x + (size_t)(m0 + r) * 1024 + kt + lc);
            As[lc + 0][r] = a4.x; As[lc + 1][r] = a4.y;
            As[lc + 2][r] = a4.z; As[lc + 3][r] = a4.w;
            float4 b4 = *(const float4*)(W + (size_t)(nb + r) * 1024 + kt + lc);
            Bs[lc + 0][r] = b4.x; Bs[lc + 1][r] = b4.y;
            Bs[lc + 2][r] = b4.z; Bs[lc + 3][r] = b4.w;
        }
        __syncthreads();
        #pragma unroll
        for (int kk = 0; kk < 32; ++kk) {
            float a[8], bb[8];
            *(float4*)&a[0]  = *(const float4*)&As[kk][tm * 4];
            *(float4*)&a[4]  = *(const float4*)&As[kk][64 + tm * 4];
            *(float4*)&bb[0] = *(const float4*)&Bs[kk][tn * 4];
            *(float4*)&bb[4] = *(const float4*)&Bs[kk][64 + tn * 4];
            #pragma unroll
            for (int i = 0; i < 8; ++i)
                #pragma unroll
                for (int j = 0; j < 8; ++j)
                    acc[i][j] = fmaf(a[i], bb[j], acc[i][j]);
        }
    }

    int mi[8], ni[8];
    #pragma unroll
    for (int i = 0; i < 4; ++i) { mi[i] = tm * 4 + i; mi[i + 4] = 64 + tm * 4 + i;
                                  ni[i] = tn * 4 + i; ni[i + 4] = 64 + tn * 4 + i; }
    float bvals[8];
    #pragma unroll
    for (int j = 0; j < 8; ++j) bvals[j] = bias[nb + ni[j]];

    #pragma unroll
    for (int i = 0; i < 8; ++i) {
        size_t row = (size_t)(m0 + mi[i]);
        #pragma unroll
        for (int j = 0; j < 8; ++j) {
            float v = acc[i][j] + bvals[j];
            int n = nb + ni[j];
            if (which == 0)      Q[row * 1024 + n] = v;
            else if (which == 1) Kb[row * 1024 + n] = __float2bfloat16(v);
            else                 Vb[row * 1024 + n] = __float2bfloat16(v);
        }
    }
}

// ---- M[b][h][l] = max_u(score) - mean_u(score), fp32 exact ----
__global__ __launch_bounds__(256) void m_kernel(const float* __restrict__ Q,
                                                const float* __restrict__ Ksamp,
                                                float* __restrict__ M, int U) {
    __shared__ float ks[64 * 64];
    int lc = blockIdx.x, h = blockIdx.y, b = blockIdx.z;
    for (int t = threadIdx.x; t < U * 64; t += 256) {
        int u = t >> 6, d = t & 63;
        ks[t] = Ksamp[((size_t)b * U + u) * D_ + h * 64 + d];
    }
    __syncthreads();
    int l = lc * 256 + threadIdx.x;
    const float* qp = Q + ((size_t)b * L_ + l) * D_ + h * 64;
    float q[64];
    #pragma unroll
    for (int i = 0; i < 16; ++i) *(float4*)&q[i * 4] = *(const float4*)(qp + i * 4);
    float mx = -INFINITY, sm = 0.f;
    for (int u = 0; u < U; ++u) {
        const float* kp = &ks[u * 64];
        float dot = 0.f;
        #pragma unroll
        for (int d = 0; d < 64; ++d) dot = fmaf(q[d], kp[d], dot);
        dot *= SCALE;
        mx = fmaxf(mx, dot);
        sm += dot;
    }
    M[((size_t)(b * H_ + h)) * L_ + l] = mx - sm / (float)U;
}

// ---- top-k via iterative argmax (min-index tie-break, matches lax.top_k set) ----
__global__ __launch_bounds__(256) void topk_kernel(const float* __restrict__ M,
                                                   int* __restrict__ topidx, int U) {
    __shared__ float vals[L_];
    __shared__ float rv[256];
    __shared__ int   ri[256];
    int bh = blockIdx.x;
    const float* mp = M + (size_t)bh * L_;
    for (int t = threadIdx.x; t < L_; t += 256) vals[t] = mp[t];
    __syncthreads();
    for (int u = 0; u < U; ++u) {
        float bv = -INFINITY; int bi = 0x7fffffff;
        for (int t = threadIdx.x; t < L_; t += 256) {
            float v = vals[t];
            if (v > bv || (v == bv && t < bi)) { bv = v; bi = t; }
        }
        rv[threadIdx.x] = bv; ri[threadIdx.x] = bi;
        __syncthreads();
        for (int s = 128; s > 0; s >>= 1) {
            if (threadIdx.x < s) {
                float v2 = rv[threadIdx.x + s]; int i2 = ri[threadIdx.x + s];
                if (v2 > rv[threadIdx.x] ||
                    (v2 == rv[threadIdx.x] && i2 < ri[threadIdx.x])) {
                    rv[threadIdx.x] = v2; ri[threadIdx.x] = i2;
                }
            }
            __syncthreads();
        }
        if (threadIdx.x == 0) { topidx[bh * U + u] = ri[0]; vals[ri[0]] = -INFINITY; }
        __syncthreads();
    }
}

// ---- flash attention for one (b,h,u) top row over all L keys ----
__global__ __launch_bounds__(256) void attn_kernel(const float* __restrict__ Q,
        const __hip_bfloat16* __restrict__ Kb, const __hip_bfloat16* __restrict__ Vb,
        const int* __restrict__ topidx, float* __restrict__ ctx_top, int U) {
    __shared__ float red_m[4], red_s[4], red_acc[4][64];
    int u = blockIdx.x, h = blockIdx.y, b = blockIdx.z;
    int row = topidx[(b * H_ + h) * U + u];
    const float* qp = Q + ((size_t)b * L_ + row) * D_ + h * 64;
    float q[64];
    #pragma unroll
    for (int i = 0; i < 16; ++i) *(float4*)&q[i * 4] = *(const float4*)(qp + i * 4);

    float m = -INFINITY, s = 0.f;
    float acc[64];
    #pragma unroll
    for (int d = 0; d < 64; ++d) acc[d] = 0.f;

    for (int l = threadIdx.x; l < L_; l += 256) {
        const uint4* kp4 = (const uint4*)(Kb + ((size_t)b * L_ + l) * D_ + h * 64);
        const uint4* vp4 = (const uint4*)(Vb + ((size_t)b * L_ + l) * D_ + h * 64);
        uint4 vw[8];
        #pragma unroll
        for (int i = 0; i < 8; ++i) vw[i] = vp4[i];
        float dot = 0.f;
        #pragma unroll
        for (int i = 0; i < 8; ++i) {
            uint4 w = kp4[i];
            unsigned c0 = w.x, c1 = w.y, c2 = w.z, c3 = w.w;
            dot = fmaf(q[i * 8 + 0], blo(c0), dot);
            dot = fmaf(q[i * 8 + 1], bhi(c0), dot);
            dot = fmaf(q[i * 8 + 2], blo(c1), dot);
            dot = fmaf(q[i * 8 + 3], bhi(c1), dot);
            dot = fmaf(q[i * 8 + 4], blo(c2), dot);
            dot = fmaf(q[i * 8 + 5], bhi(c2), dot);
            dot = fmaf(q[i * 8 + 6], blo(c3), dot);
            dot = fmaf(q[i * 8 + 7], bhi(c3), dot);
        }
        dot *= SCALE;
        if (dot <= m) {
            float p = __expf(dot - m);
            s += p;
            #pragma unroll
            for (int i = 0; i < 8; ++i) {
                unsigned c0 = vw[i].x, c1 = vw[i].y, c2 = vw[i].z, c3 = vw[i].w;
                acc[i * 8 + 0] = fmaf(p, blo(c0), acc[i * 8 + 0]);
                acc[i * 8 + 1] = fmaf(p, bhi(c0), acc[i * 8 + 1]);
                acc[i * 8 + 2] = fmaf(p, blo(c1), acc[i * 8 + 2]);
                acc[i * 8 + 3] = fmaf(p, bhi(c1), acc[i * 8 + 3]);
                acc[i * 8 + 4] = fmaf(p, blo(c2), acc[i * 8 + 4]);
                acc[i * 8 + 5] = fmaf(p, bhi(c2), acc[i * 8 + 5]);
                acc[i * 8 + 6] = fmaf(p, blo(c3), acc[i * 8 + 6]);
                acc[i * 8 + 7] = fmaf(p, bhi(c3), acc[i * 8 + 7]);
            }
        } else {
            float f = __expf(m - dot);
            s = fmaf(s, f, 1.0f);
            #pragma unroll
            for (int i = 0; i < 8; ++i) {
                unsigned c0 = vw[i].x, c1 = vw[i].y, c2 = vw[i].z, c3 = vw[i].w;
                acc[i * 8 + 0] = fmaf(acc[i * 8 + 0], f, blo(c0));
                acc[i * 8 + 1] = fmaf(acc[i * 8 + 1], f, bhi(c0));
                acc[i * 8 + 2] = fmaf(acc[i * 8 + 2], f, blo(c1));
                acc[i * 8 + 3] = fmaf(acc[i * 8 + 3], f, bhi(c1));
                acc[i * 8 + 4] = fmaf(acc[i * 8 + 4], f, blo(c2));
                acc[i * 8 + 5] = fmaf(acc[i * 8 + 5], f, bhi(c2));
                acc[i * 8 + 6] = fmaf(acc[i * 8 + 6], f, blo(c3));
                acc[i * 8 + 7] = fmaf(acc[i * 8 + 7], f, bhi(c3));
            }
            m = dot;
        }
    }

    // 64-lane butterfly reduce of (m, s, acc[64])
    #pragma unroll
    for (int off = 32; off > 0; off >>= 1) {
        float om = __shfl_xor(m, off, 64);
        float os = __shfl_xor(s, off, 64);
        float nm = fmaxf(m, om);
        float f1 = __expf(m - nm), f2 = __expf(om - nm);
        s = s * f1 + os * f2;
        #pragma unroll
        for (int d = 0; d < 64; ++d) {
            float oa = __shfl_xor(acc[d], off, 64);
            acc[d] = acc[d] * f1 + oa * f2;
        }
        m = nm;
    }
    int wv = threadIdx.x >> 6, ln = threadIdx.x & 63;
    if (ln == 0) { red_m[wv] = m; red_s[wv] = s; }
    red_acc[wv][ln] = acc[ln];
    __syncthreads();
    if (threadIdx.x < 64) {
        int d = threadIdx.x;
        float Mx = fmaxf(fmaxf(red_m[0], red_m[1]), fmaxf(red_m[2], red_m[3]));
        float S = 0.f, A = 0.f;
        #pragma unroll
        for (int w = 0; w < 4; ++w) {
            float f = __expf(red_m[w] - Mx);
            S += red_s[w] * f;
            A += red_acc[w][d] * f;
        }
        ctx_top[(((size_t)(b * H_ + h)) * U + u) * 64 + d] = A / S;
    }
}

// ---- out[b][l][:] = base[b][:] for all rows ----
__global__ __launch_bounds__(256) void fill_base_kernel(const float* __restrict__ base,
                                                        float* __restrict__ out) {
    size_t i = (size_t)blockIdx.x * 256 + threadIdx.x;   // float4 index
    int col4 = (int)(i & 255);
    int b = (int)(i >> 21);
    ((float4*)out)[i] = ((const float4*)base)[b * 256 + col4];
}

// ---- out[b][row][:] += (ctx_top - vmean_h) @ Wo_h.T  (atomic: rows can repeat across h) ----
__global__ __launch_bounds__(256) void delta_kernel(const float* __restrict__ ctx_top,
        const float* __restrict__ vmean, const float* __restrict__ Wo,
        const int* __restrict__ topidx, float* __restrict__ out, int U) {
    __shared__ float cd[64];
    int u = blockIdx.x, h = blockIdx.y, b = blockIdx.z;
    int row = topidx[(b * H_ + h) * U + u];
    if (threadIdx.x < 64) {
        cd[threadIdx.x] = ctx_top[(((size_t)(b * H_ + h)) * U + u) * 64 + threadIdx.x]
                        - vmean[b * D_ + h * 64 + threadIdx.x];
    }
    __syncthreads();
    float* op = out + ((size_t)b * L_ + row) * D_;
    #pragma unroll
    for (int r = 0; r < 4; ++r) {
        int j = r * 256 + threadIdx.x;
        const float* wr = Wo + (size_t)j * D_ + h * 64;
        float dlt = 0.f;
        #pragma unroll
        for (int k = 0; k < 64; k += 4) {
            float4 w4 = *(const float4*)(wr + k);
            dlt += cd[k] * w4.x + cd[k + 1] * w4.y + cd[k + 2] * w4.z + cd[k + 3] * w4.w;
        }
        atomicAdd(op + j, dlt);
    }
}

extern "C" void kernel_launch(void* const* d_in, const int* in_sizes, int n_in,
                              void* d_out, int out_size, void* d_ws, size_t ws_size,
                              hipStream_t stream) {
    const float* x   = (const float*)d_in[0];
    const float* Wq  = (const float*)d_in[1];
    const float* bq  = (const float*)d_in[2];
    const float* Wk  = (const float*)d_in[3];
    const float* bk  = (const float*)d_in[4];
    const float* Wv  = (const float*)d_in[5];
    const float* bv  = (const float*)d_in[6];
    const float* Wo  = (const float*)d_in[7];
    const float* bo  = (const float*)d_in[8];
    const int* idx_k = (const int*)d_in[9];
    const int U = in_sizes[9];
    float* out = (float*)d_out;
    (void)n_in; (void)ws_size;

    char* ws = (char*)d_ws;
    size_t off = 0;
    auto alloc = [&](size_t bytes) -> void* {
        void* p = ws + off;
        off += (bytes + 255) & ~(size_t)255;
        return p;
    };
    float* Q              = (float*)alloc((size_t)B_ * L_ * D_ * 4);
    __hip_bfloat16* Kb    = (__hip_bfloat16*)alloc((size_t)B_ * L_ * D_ * 2);
    __hip_bfloat16* Vb    = (__hip_bfloat16*)alloc((size_t)B_ * L_ * D_ * 2);
    float* Ksamp          = (float*)alloc((size_t)B_ * U * D_ * 4);
    float* Mbuf           = (float*)alloc((size_t)B_ * H_ * L_ * 4);
    int*   topidx         = (int*)alloc((size_t)B_ * H_ * U * 4);
    float* xmean          = (float*)alloc((size_t)B_ * D_ * 4);
    float* vmean          = (float*)alloc((size_t)B_ * D_ * 4);
    float* base           = (float*)alloc((size_t)B_ * D_ * 4);
    float* ctxt           = (float*)alloc((size_t)B_ * H_ * U * 64 * 4);

    hipMemsetAsync(xmean, 0, (size_t)B_ * D_ * 4, stream);
    xmean_kernel<<<dim3(32, 4, B_), 256, 0, stream>>>(x, xmean);
    vecmat_kernel<<<dim3(4, B_), 256, 0, stream>>>(xmean, Wv, bv, vmean);
    vecmat_kernel<<<dim3(4, B_), 256, 0, stream>>>(vmean, Wo, bo, base);
    ksamp_kernel<<<dim3(U, B_), 256, 0, stream>>>(x, Wk, bk, idx_k, Ksamp, U);
    qkv_gemm<<<dim3(24, 256), 256, 0, stream>>>(x, Wq, bq, Wk, bk, Wv, bv, Q, Kb, Vb);
    m_kernel<<<dim3(32, H_, B_), 256, 0, stream>>>(Q, Ksamp, Mbuf, U);
    topk_kernel<<<dim3(B_ * H_), 256, 0, stream>>>(Mbuf, topidx, U);
    attn_kernel<<<dim3(U, H_, B_), 256, 0, stream>>>(Q, Kb, Vb, topidx, ctxt, U);
    fill_base_kernel<<<dim3(out_size / 4 / 256), 256, 0, stream>>>(base, out);
    delta_kernel<<<dim3(U, H_, B_), 256, 0, stream>>>(ctxt, vmean, Wo, topidx, out, U);
}

// Round 2
// 4256.809 us; speedup vs baseline: 1.3152x; 1.3152x over previous
//
#include <hip/hip_runtime.h>
#include <hip/hip_bf16.h>

#define B_ 4
#define L_ 8192
#define D_ 1024
#define H_ 16
#define SCALE 0.125f

typedef __attribute__((ext_vector_type(8))) short bf16x8;
typedef __attribute__((ext_vector_type(4))) float f32x4;

__device__ __forceinline__ float blo(unsigned v) { return __uint_as_float(v << 16); }
__device__ __forceinline__ float bhi(unsigned v) { return __uint_as_float(v & 0xffff0000u); }

__device__ __forceinline__ void gl2lds16(const void* g, void* s) {
    __builtin_amdgcn_global_load_lds(
        (const __attribute__((address_space(1))) unsigned int*)g,
        (__attribute__((address_space(3))) unsigned int*)s, 16, 0, 0);
}

__device__ __forceinline__ unsigned short bfbits(float a) {
    __hip_bfloat16 h = __float2bfloat16(a);
    return *(unsigned short*)&h;
}
__device__ __forceinline__ float bf2f(unsigned short u) {
    return __uint_as_float(((unsigned)u) << 16);
}

// ---- split fp32 -> 3 bf16 terms (hi+mid+lo reproduces fp32 to ~2^-27) ----
__global__ __launch_bounds__(256) void split3_kernel(const float* __restrict__ in,
        unsigned short* __restrict__ ph, unsigned short* __restrict__ pm,
        unsigned short* __restrict__ pl, int n4) {
    int i = blockIdx.x * 256 + threadIdx.x;
    if (i >= n4) return;
    float4 v = ((const float4*)in)[i];
    float c[4] = {v.x, v.y, v.z, v.w};
    unsigned short h[4], m[4], l[4];
    #pragma unroll
    for (int j = 0; j < 4; ++j) {
        float a = c[j];
        unsigned short hb = bfbits(a);
        float rh = a - bf2f(hb);
        unsigned short mb = bfbits(rh);
        float rm = rh - bf2f(mb);
        unsigned short lb = bfbits(rm);
        h[j] = hb; m[j] = mb; l[j] = lb;
    }
    ((ushort4*)ph)[i] = *(ushort4*)h;
    ((ushort4*)pm)[i] = *(ushort4*)m;
    ((ushort4*)pl)[i] = *(ushort4*)l;
}

__global__ __launch_bounds__(256) void split2_kernel(const float* __restrict__ in,
        unsigned short* __restrict__ ph, unsigned short* __restrict__ pm, int n4) {
    int i = blockIdx.x * 256 + threadIdx.x;
    if (i >= n4) return;
    float4 v = ((const float4*)in)[i];
    float c[4] = {v.x, v.y, v.z, v.w};
    unsigned short h[4], m[4];
    #pragma unroll
    for (int j = 0; j < 4; ++j) {
        float a = c[j];
        unsigned short hb = bfbits(a);
        float rh = a - bf2f(hb);
        h[j] = hb; m[j] = bfbits(rh);
    }
    ((ushort4*)ph)[i] = *(ushort4*)h;
    ((ushort4*)pm)[i] = *(ushort4*)m;
}

// ---- xmean[b][j] = mean over l of x[b][l][j] ----
__global__ __launch_bounds__(256) void xmean_kernel(const float* __restrict__ x,
                                                    float* __restrict__ xmean) {
    int c = blockIdx.x;
    int j = blockIdx.y * 256 + threadIdx.x;
    int b = blockIdx.z;
    const float* xp = x + ((size_t)b * L_ + (size_t)c * 256) * D_ + j;
    float s = 0.f;
    for (int l = 0; l < 256; ++l) s += xp[(size_t)l * D_];
    atomicAdd(&xmean[b * D_ + j], s * (1.0f / L_));
}

// ---- out[b][j] = dot(in[b], W[j]) + bias[j] ----
__global__ __launch_bounds__(256) void vecmat_kernel(const float* __restrict__ in,
                                                     const float* __restrict__ W,
                                                     const float* __restrict__ bias,
                                                     float* __restrict__ out) {
    __shared__ float vs[D_];
    int b = blockIdx.y;
    int j = blockIdx.x * 256 + threadIdx.x;
    for (int t = threadIdx.x; t < D_; t += 256) vs[t] = in[b * D_ + t];
    __syncthreads();
    const float* wr = W + (size_t)j * D_;
    float acc = 0.f;
    #pragma unroll 4
    for (int k = 0; k < D_; k += 4) {
        float4 w4 = *(const float4*)(wr + k);
        acc += vs[k] * w4.x + vs[k + 1] * w4.y + vs[k + 2] * w4.z + vs[k + 3] * w4.w;
    }
    out[b * D_ + j] = acc + bias[j];
}

// ---- Ksamp[b][u][:] = x[b][idx_k[u]] @ Wk.T + bk  (fp32 exact, selection path) ----
__global__ __launch_bounds__(256) void ksamp_kernel(const float* __restrict__ x,
                                                    const float* __restrict__ Wk,
                                                    const float* __restrict__ bk,
                                                    const int* __restrict__ idx_k,
                                                    float* __restrict__ Ksamp, int U) {
    __shared__ float vs[D_];
    int u = blockIdx.x, b = blockIdx.y;
    int row = idx_k[u];
    const float* xp = x + ((size_t)b * L_ + row) * D_;
    for (int t = threadIdx.x; t < D_; t += 256) vs[t] = xp[t];
    __syncthreads();
    #pragma unroll
    for (int r = 0; r < 4; ++r) {
        int j = r * 256 + threadIdx.x;
        const float* wr = Wk + (size_t)j * D_;
        float acc = 0.f;
        #pragma unroll 4
        for (int k = 0; k < D_; k += 4) {
            float4 w4 = *(const float4*)(wr + k);
            acc += vs[k] * w4.x + vs[k + 1] * w4.y + vs[k + 2] * w4.z + vs[k + 3] * w4.w;
        }
        Ksamp[((size_t)b * U + u) * D_ + j] = acc + bk[j];
    }
}

// ---- fused QKV via split-bf16 MFMA (m97 structure: 128x128 tile, BK=32) ----
// Q: 6 products (fp32-class, selection-critical); K,V: 3 products (~2^-17, stored bf16).
#define TM 128
#define TN 128
#define BK 32

__global__ __launch_bounds__(256) void qkv_mfma(
    const unsigned short* __restrict__ xh, const unsigned short* __restrict__ xm,
    const unsigned short* __restrict__ xl,
    const unsigned short* __restrict__ qh, const unsigned short* __restrict__ qm,
    const unsigned short* __restrict__ ql,
    const unsigned short* __restrict__ kh, const unsigned short* __restrict__ km,
    const unsigned short* __restrict__ vh, const unsigned short* __restrict__ vm,
    const float* __restrict__ bq, const float* __restrict__ bk2, const float* __restrict__ bv,
    float* __restrict__ Q, __hip_bfloat16* __restrict__ Kb, __hip_bfloat16* __restrict__ Vb) {
    __shared__ __align__(16) unsigned short As[TM * BK];
    __shared__ __align__(16) unsigned short Bs[TN * BK];

    const int n0 = blockIdx.x * TN;
    const int m0 = blockIdx.y * TM;
    const int tid = threadIdx.x;

    const unsigned short* Ap[6]; const unsigned short* Bp[6]; int P;
    const float* bias; int which; int nb;
    if (n0 < 1024) {
        which = 0; nb = n0; bias = bq; P = 6;
        Ap[0] = xh; Bp[0] = qh; Ap[1] = xh; Bp[1] = qm; Ap[2] = xm; Bp[2] = qh;
        Ap[3] = xh; Bp[3] = ql; Ap[4] = xm; Bp[4] = qm; Ap[5] = xl; Bp[5] = qh;
    } else if (n0 < 2048) {
        which = 1; nb = n0 - 1024; bias = bk2; P = 3;
        Ap[0] = xh; Bp[0] = kh; Ap[1] = xh; Bp[1] = km; Ap[2] = xm; Bp[2] = kh;
    } else {
        which = 2; nb = n0 - 2048; bias = bv; P = 3;
        Ap[0] = xh; Bp[0] = vh; Ap[1] = xh; Bp[1] = vm; Ap[2] = xm; Bp[2] = vh;
    }

    const int srow = tid >> 2;            // staging row 0..63 (seg1: +64)
    const int scol = (tid & 3) * 8;       // staging k-offset (8 bf16 = 16 B)

    const int wave = tid >> 6;
    const int lane = tid & 63;
    const int wm = (wave & 1) * 64;
    const int wn = (wave >> 1) * 64;
    const int fr = lane & 15;             // A: m within 16-tile; B: n within 16-tile
    const int fk = (lane >> 4) * 8;       // k offset within 32
    const int rbase = (lane >> 4) * 4;    // C/D row base

    f32x4 acc[4][4];
    #pragma unroll
    for (int i = 0; i < 4; ++i)
        #pragma unroll
        for (int j = 0; j < 4; ++j)
            acc[i][j] = (f32x4){0.f, 0.f, 0.f, 0.f};

    unsigned short* lA = As + tid * 8;    // dest = wave-uniform base + lane*16B
    unsigned short* lB = Bs + tid * 8;

    for (int p = 0; p < P; ++p) {
        const unsigned short* Aq = Ap[p] + (size_t)m0 * D_;
        const unsigned short* Bq = Bp[p] + (size_t)nb * D_;
        for (int kt = 0; kt < D_; kt += BK) {
            gl2lds16(Aq + (size_t)srow * D_ + kt + scol, lA);
            gl2lds16(Aq + (size_t)(srow + 64) * D_ + kt + scol, lA + 2048);
            gl2lds16(Bq + (size_t)srow * D_ + kt + scol, lB);
            gl2lds16(Bq + (size_t)(srow + 64) * D_ + kt + scol, lB + 2048);
            __syncthreads();
            bf16x8 af[4], bfr[4];
            #pragma unroll
            for (int i = 0; i < 4; ++i) {
                af[i]  = *(const bf16x8*)(As + (wm + i * 16 + fr) * BK + fk);
                bfr[i] = *(const bf16x8*)(Bs + (wn + i * 16 + fr) * BK + fk);
            }
            #pragma unroll
            for (int i = 0; i < 4; ++i)
                #pragma unroll
                for (int j = 0; j < 4; ++j)
                    acc[i][j] = __builtin_amdgcn_mfma_f32_16x16x32_bf16(
                        af[i], bfr[j], acc[i][j], 0, 0, 0);
            __syncthreads();
        }
    }

    float biasv[4];
    #pragma unroll
    for (int j = 0; j < 4; ++j) biasv[j] = bias[nb + wn + j * 16 + fr];

    #pragma unroll
    for (int i = 0; i < 4; ++i) {
        #pragma unroll
        for (int r = 0; r < 4; ++r) {
            size_t row = (size_t)(m0 + wm + i * 16 + rbase + r);
            #pragma unroll
            for (int j = 0; j < 4; ++j) {
                float v = acc[i][j][r] + biasv[j];
                int n = nb + wn + j * 16 + fr;
                if (which == 0)      Q[row * D_ + n] = v;
                else if (which == 1) Kb[row * D_ + n] = __float2bfloat16(v);
                else                 Vb[row * D_ + n] = __float2bfloat16(v);
            }
        }
    }
}

// ---- M[b][h][l] = max_u(score) - mean_u(score), fp32 exact ----
__global__ __launch_bounds__(256) void m_kernel(const float* __restrict__ Q,
                                                const float* __restrict__ Ksamp,
                                                float* __restrict__ M, int U) {
    __shared__ float ks[64 * 64];
    int lc = blockIdx.x, h = blockIdx.y, b = blockIdx.z;
    for (int t = threadIdx.x; t < U * 64; t += 256) {
        int u = t >> 6, d = t & 63;
        ks[t] = Ksamp[((size_t)b * U + u) * D_ + h * 64 + d];
    }
    __syncthreads();
    int l = lc * 256 + threadIdx.x;
    const float* qp = Q + ((size_t)b * L_ + l) * D_ + h * 64;
    float q[64];
    #pragma unroll
    for (int i = 0; i < 16; ++i) *(float4*)&q[i * 4] = *(const float4*)(qp + i * 4);
    float mx = -INFINITY, sm = 0.f;
    for (int u = 0; u < U; ++u) {
        const float* kp = &ks[u * 64];
        float dot = 0.f;
        #pragma unroll
        for (int d = 0; d < 64; ++d) dot = fmaf(q[d], kp[d], dot);
        dot *= SCALE;
        mx = fmaxf(mx, dot);
        sm += dot;
    }
    M[((size_t)(b * H_ + h)) * L_ + l] = mx - sm / (float)U;
}

// ---- top-k via iterative argmax ----
__global__ __launch_bounds__(256) void topk_kernel(const float* __restrict__ M,
                                                   int* __restrict__ topidx, int U) {
    __shared__ float vals[L_];
    __shared__ float rv[256];
    __shared__ int   ri[256];
    int bh = blockIdx.x;
    const float* mp = M + (size_t)bh * L_;
    for (int t = threadIdx.x; t < L_; t += 256) vals[t] = mp[t];
    __syncthreads();
    for (int u = 0; u < U; ++u) {
        float bv = -INFINITY; int bi = 0x7fffffff;
        for (int t = threadIdx.x; t < L_; t += 256) {
            float v = vals[t];
            if (v > bv || (v == bv && t < bi)) { bv = v; bi = t; }
        }
        rv[threadIdx.x] = bv; ri[threadIdx.x] = bi;
        __syncthreads();
        for (int s = 128; s > 0; s >>= 1) {
            if (threadIdx.x < s) {
                float v2 = rv[threadIdx.x + s]; int i2 = ri[threadIdx.x + s];
                if (v2 > rv[threadIdx.x] ||
                    (v2 == rv[threadIdx.x] && i2 < ri[threadIdx.x])) {
                    rv[threadIdx.x] = v2; ri[threadIdx.x] = i2;
                }
            }
            __syncthreads();
        }
        if (threadIdx.x == 0) { topidx[bh * U + u] = ri[0]; vals[ri[0]] = -INFINITY; }
        __syncthreads();
    }
}

// ---- flash attention for one (b,h,u) top row over all L keys ----
__global__ __launch_bounds__(256) void attn_kernel(const float* __restrict__ Q,
        const __hip_bfloat16* __restrict__ Kb, const __hip_bfloat16* __restrict__ Vb,
        const int* __restrict__ topidx, float* __restrict__ ctx_top, int U) {
    __shared__ float red_m[4], red_s[4], red_acc[4][64];
    int u = blockIdx.x, h = blockIdx.y, b = blockIdx.z;
    int row = topidx[(b * H_ + h) * U + u];
    const float* qp = Q + ((size_t)b * L_ + row) * D_ + h * 64;
    float q[64];
    #pragma unroll
    for (int i = 0; i < 16; ++i) *(float4*)&q[i * 4] = *(const float4*)(qp + i * 4);

    float m = -INFINITY, s = 0.f;
    float acc[64];
    #pragma unroll
    for (int d = 0; d < 64; ++d) acc[d] = 0.f;

    for (int l = threadIdx.x; l < L_; l += 256) {
        const uint4* kp4 = (const uint4*)(Kb + ((size_t)b * L_ + l) * D_ + h * 64);
        const uint4* vp4 = (const uint4*)(Vb + ((size_t)b * L_ + l) * D_ + h * 64);
        uint4 vw[8];
        #pragma unroll
        for (int i = 0; i < 8; ++i) vw[i] = vp4[i];
        float dot = 0.f;
        #pragma unroll
        for (int i = 0; i < 8; ++i) {
            uint4 w = kp4[i];
            unsigned c0 = w.x, c1 = w.y, c2 = w.z, c3 = w.w;
            dot = fmaf(q[i * 8 + 0], blo(c0), dot);
            dot = fmaf(q[i * 8 + 1], bhi(c0), dot);
            dot = fmaf(q[i * 8 + 2], blo(c1), dot);
            dot = fmaf(q[i * 8 + 3], bhi(c1), dot);
            dot = fmaf(q[i * 8 + 4], blo(c2), dot);
            dot = fmaf(q[i * 8 + 5], bhi(c2), dot);
            dot = fmaf(q[i * 8 + 6], blo(c3), dot);
            dot = fmaf(q[i * 8 + 7], bhi(c3), dot);
        }
        dot *= SCALE;
        if (dot <= m) {
            float p = __expf(dot - m);
            s += p;
            #pragma unroll
            for (int i = 0; i < 8; ++i) {
                unsigned c0 = vw[i].x, c1 = vw[i].y, c2 = vw[i].z, c3 = vw[i].w;
                acc[i * 8 + 0] = fmaf(p, blo(c0), acc[i * 8 + 0]);
                acc[i * 8 + 1] = fmaf(p, bhi(c0), acc[i * 8 + 1]);
                acc[i * 8 + 2] = fmaf(p, blo(c1), acc[i * 8 + 2]);
                acc[i * 8 + 3] = fmaf(p, bhi(c1), acc[i * 8 + 3]);
                acc[i * 8 + 4] = fmaf(p, blo(c2), acc[i * 8 + 4]);
                acc[i * 8 + 5] = fmaf(p, bhi(c2), acc[i * 8 + 5]);
                acc[i * 8 + 6] = fmaf(p, blo(c3), acc[i * 8 + 6]);
                acc[i * 8 + 7] = fmaf(p, bhi(c3), acc[i * 8 + 7]);
            }
        } else {
            float f = __expf(m - dot);
            s = fmaf(s, f, 1.0f);
            #pragma unroll
            for (int i = 0; i < 8; ++i) {
                unsigned c0 = vw[i].x, c1 = vw[i].y, c2 = vw[i].z, c3 = vw[i].w;
                acc[i * 8 + 0] = fmaf(acc[i * 8 + 0], f, blo(c0));
                acc[i * 8 + 1] = fmaf(acc[i * 8 + 1], f, bhi(c0));
                acc[i * 8 + 2] = fmaf(acc[i * 8 + 2], f, blo(c1));
                acc[i * 8 + 3] = fmaf(acc[i * 8 + 3], f, bhi(c1));
                acc[i * 8 + 4] = fmaf(acc[i * 8 + 4], f, blo(c2));
                acc[i * 8 + 5] = fmaf(acc[i * 8 + 5], f, bhi(c2));
                acc[i * 8 + 6] = fmaf(acc[i * 8 + 6], f, blo(c3));
                acc[i * 8 + 7] = fmaf(acc[i * 8 + 7], f, bhi(c3));
            }
            m = dot;
        }
    }

    #pragma unroll
    for (int off = 32; off > 0; off >>= 1) {
        float om = __shfl_xor(m, off, 64);
        float os = __shfl_xor(s, off, 64);
        float nm = fmaxf(m, om);
        float f1 = __expf(m - nm), f2 = __expf(om - nm);
        s = s * f1 + os * f2;
        #pragma unroll
        for (int d = 0; d < 64; ++d) {
            float oa = __shfl_xor(acc[d], off, 64);
            acc[d] = acc[d] * f1 + oa * f2;
        }
        m = nm;
    }
    int wv = threadIdx.x >> 6, ln = threadIdx.x & 63;
    if (ln == 0) { red_m[wv] = m; red_s[wv] = s; }
    red_acc[wv][ln] = acc[ln];
    __syncthreads();
    if (threadIdx.x < 64) {
        int d = threadIdx.x;
        float Mx = fmaxf(fmaxf(red_m[0], red_m[1]), fmaxf(red_m[2], red_m[3]));
        float S = 0.f, A = 0.f;
        #pragma unroll
        for (int w = 0; w < 4; ++w) {
            float f = __expf(red_m[w] - Mx);
            S += red_s[w] * f;
            A += red_acc[w][d] * f;
        }
        ctx_top[(((size_t)(b * H_ + h)) * U + u) * 64 + d] = A / S;
    }
}

// ---- out[b][l][:] = base[b][:] ----
__global__ __launch_bounds__(256) void fill_base_kernel(const float* __restrict__ base,
                                                        float* __restrict__ out) {
    size_t i = (size_t)blockIdx.x * 256 + threadIdx.x;
    int col4 = (int)(i & 255);
    int b = (int)(i >> 21);
    ((float4*)out)[i] = ((const float4*)base)[b * 256 + col4];
}

// ---- out[b][row][:] += (ctx_top - vmean_h) @ Wo_h.T ----
__global__ __launch_bounds__(256) void delta_kernel(const float* __restrict__ ctx_top,
        const float* __restrict__ vmean, const float* __restrict__ Wo,
        const int* __restrict__ topidx, float* __restrict__ out, int U) {
    __shared__ float cd[64];
    int u = blockIdx.x, h = blockIdx.y, b = blockIdx.z;
    int row = topidx[(b * H_ + h) * U + u];
    if (threadIdx.x < 64) {
        cd[threadIdx.x] = ctx_top[(((size_t)(b * H_ + h)) * U + u) * 64 + threadIdx.x]
                        - vmean[b * D_ + h * 64 + threadIdx.x];
    }
    __syncthreads();
    float* op = out + ((size_t)b * L_ + row) * D_;
    #pragma unroll
    for (int r = 0; r < 4; ++r) {
        int j = r * 256 + threadIdx.x;
        const float* wr = Wo + (size_t)j * D_ + h * 64;
        float dlt = 0.f;
        #pragma unroll
        for (int k = 0; k < 64; k += 4) {
            float4 w4 = *(const float4*)(wr + k);
            dlt += cd[k] * w4.x + cd[k + 1] * w4.y + cd[k + 2] * w4.z + cd[k + 3] * w4.w;
        }
        atomicAdd(op + j, dlt);
    }
}

extern "C" void kernel_launch(void* const* d_in, const int* in_sizes, int n_in,
                              void* d_out, int out_size, void* d_ws, size_t ws_size,
                              hipStream_t stream) {
    const float* x   = (const float*)d_in[0];
    const float* Wq  = (const float*)d_in[1];
    const float* bq  = (const float*)d_in[2];
    const float* Wk  = (const float*)d_in[3];
    const float* bk  = (const float*)d_in[4];
    const float* Wv  = (const float*)d_in[5];
    const float* bv  = (const float*)d_in[6];
    const float* Wo  = (const float*)d_in[7];
    const float* bo  = (const float*)d_in[8];
    const int* idx_k = (const int*)d_in[9];
    const int U = in_sizes[9];
    float* out = (float*)d_out;
    (void)n_in; (void)ws_size; (void)bo;

    char* ws = (char*)d_ws;
    size_t off = 0;
    auto alloc = [&](size_t bytes) -> void* {
        void* p = ws + off;
        off += (bytes + 255) & ~(size_t)255;
        return p;
    };
    float* Q              = (float*)alloc((size_t)B_ * L_ * D_ * 4);
    __hip_bfloat16* Kb    = (__hip_bfloat16*)alloc((size_t)B_ * L_ * D_ * 2);
    __hip_bfloat16* Vb    = (__hip_bfloat16*)alloc((size_t)B_ * L_ * D_ * 2);
    unsigned short* xh    = (unsigned short*)alloc((size_t)B_ * L_ * D_ * 2);
    unsigned short* xm    = (unsigned short*)alloc((size_t)B_ * L_ * D_ * 2);
    unsigned short* xl    = (unsigned short*)alloc((size_t)B_ * L_ * D_ * 2);
    unsigned short* wqh   = (unsigned short*)alloc((size_t)D_ * D_ * 2);
    unsigned short* wqm   = (unsigned short*)alloc((size_t)D_ * D_ * 2);
    unsigned short* wql   = (unsigned short*)alloc((size_t)D_ * D_ * 2);
    unsigned short* wkh   = (unsigned short*)alloc((size_t)D_ * D_ * 2);
    unsigned short* wkm   = (unsigned short*)alloc((size_t)D_ * D_ * 2);
    unsigned short* wvh   = (unsigned short*)alloc((size_t)D_ * D_ * 2);
    unsigned short* wvm   = (unsigned short*)alloc((size_t)D_ * D_ * 2);
    float* Ksamp          = (float*)alloc((size_t)B_ * U * D_ * 4);
    float* Mbuf           = (float*)alloc((size_t)B_ * H_ * L_ * 4);
    int*   topidx         = (int*)alloc((size_t)B_ * H_ * U * 4);
    float* xmean          = (float*)alloc((size_t)B_ * D_ * 4);
    float* vmean          = (float*)alloc((size_t)B_ * D_ * 4);
    float* base           = (float*)alloc((size_t)B_ * D_ * 4);
    float* ctxt           = (float*)alloc((size_t)B_ * H_ * U * 64 * 4);

    hipMemsetAsync(xmean, 0, (size_t)B_ * D_ * 4, stream);
    xmean_kernel<<<dim3(32, 4, B_), 256, 0, stream>>>(x, xmean);
    vecmat_kernel<<<dim3(4, B_), 256, 0, stream>>>(xmean, Wv, bv, vmean);
    vecmat_kernel<<<dim3(4, B_), 256, 0, stream>>>(vmean, Wo, bo, base);
    ksamp_kernel<<<dim3(U, B_), 256, 0, stream>>>(x, Wk, bk, idx_k, Ksamp, U);

    const int n4x = B_ * L_ * D_ / 4;
    const int n4w = D_ * D_ / 4;
    split3_kernel<<<dim3(n4x / 256), 256, 0, stream>>>(x, xh, xm, xl, n4x);
    split3_kernel<<<dim3(n4w / 256), 256, 0, stream>>>(Wq, wqh, wqm, wql, n4w);
    split2_kernel<<<dim3(n4w / 256), 256, 0, stream>>>(Wk, wkh, wkm, n4w);
    split2_kernel<<<dim3(n4w / 256), 256, 0, stream>>>(Wv, wvh, wvm, n4w);

    qkv_mfma<<<dim3(24, 256), 256, 0, stream>>>(xh, xm, xl, wqh, wqm, wql,
                                                wkh, wkm, wvh, wvm,
                                                bq, bk, bv, Q, Kb, Vb);

    m_kernel<<<dim3(32, H_, B_), 256, 0, stream>>>(Q, Ksamp, Mbuf, U);
    topk_kernel<<<dim3(B_ * H_), 256, 0, stream>>>(Mbuf, topidx, U);
    attn_kernel<<<dim3(U, H_, B_), 256, 0, stream>>>(Q, Kb, Vb, topidx, ctxt, U);
    fill_base_kernel<<<dim3(out_size / 4 / 256), 256, 0, stream>>>(base, out);
    delta_kernel<<<dim3(U, H_, B_), 256, 0, stream>>>(ctxt, vmean, Wo, topidx, out, U);
}

// Round 3
// 1997.859 us; speedup vs baseline: 2.8023x; 2.1307x over previous
//
#include <hip/hip_runtime.h>
#include <hip/hip_bf16.h>

#define B_ 4
#define L_ 8192
#define D_ 1024
#define H_ 16
#define SCALE 0.125f
#define NC 8            // attention L-chunks
#define QPAD 64         // padded query count (U=50 -> 64)
#define RS 72           // LDS row stride in ushort (64 + 8 pad)

typedef __attribute__((ext_vector_type(8))) short bf16x8;
typedef __attribute__((ext_vector_type(4))) float f32x4;

__device__ __forceinline__ float blo(unsigned v) { return __uint_as_float(v << 16); }
__device__ __forceinline__ float bhi(unsigned v) { return __uint_as_float(v & 0xffff0000u); }

__device__ __forceinline__ void gl2lds16(const void* g, void* s) {
    __builtin_amdgcn_global_load_lds(
        (const __attribute__((address_space(1))) unsigned int*)g,
        (__attribute__((address_space(3))) unsigned int*)s, 16, 0, 0);
}

__device__ __forceinline__ unsigned short bfbits(float a) {
    __hip_bfloat16 h = __float2bfloat16(a);
    return *(unsigned short*)&h;
}
__device__ __forceinline__ float bf2f(unsigned short u) {
    return __uint_as_float(((unsigned)u) << 16);
}

// ---- split fp32 -> 3 bf16 terms ----
__global__ __launch_bounds__(256) void split3_kernel(const float* __restrict__ in,
        unsigned short* __restrict__ ph, unsigned short* __restrict__ pm,
        unsigned short* __restrict__ pl, int n4) {
    int i = blockIdx.x * 256 + threadIdx.x;
    if (i >= n4) return;
    float4 v = ((const float4*)in)[i];
    float c[4] = {v.x, v.y, v.z, v.w};
    unsigned short h[4], m[4], l[4];
    #pragma unroll
    for (int j = 0; j < 4; ++j) {
        float a = c[j];
        unsigned short hb = bfbits(a);
        float rh = a - bf2f(hb);
        unsigned short mb = bfbits(rh);
        float rm = rh - bf2f(mb);
        h[j] = hb; m[j] = mb; l[j] = bfbits(rm);
    }
    ((ushort4*)ph)[i] = *(ushort4*)h;
    ((ushort4*)pm)[i] = *(ushort4*)m;
    ((ushort4*)pl)[i] = *(ushort4*)l;
}

__global__ __launch_bounds__(256) void split2_kernel(const float* __restrict__ in,
        unsigned short* __restrict__ ph, unsigned short* __restrict__ pm, int n4) {
    int i = blockIdx.x * 256 + threadIdx.x;
    if (i >= n4) return;
    float4 v = ((const float4*)in)[i];
    float c[4] = {v.x, v.y, v.z, v.w};
    unsigned short h[4], m[4];
    #pragma unroll
    for (int j = 0; j < 4; ++j) {
        float a = c[j];
        unsigned short hb = bfbits(a);
        float rh = a - bf2f(hb);
        h[j] = hb; m[j] = bfbits(rh);
    }
    ((ushort4*)ph)[i] = *(ushort4*)h;
    ((ushort4*)pm)[i] = *(ushort4*)m;
}

// ---- xmean ----
__global__ __launch_bounds__(256) void xmean_kernel(const float* __restrict__ x,
                                                    float* __restrict__ xmean) {
    int c = blockIdx.x;
    int j = blockIdx.y * 256 + threadIdx.x;
    int b = blockIdx.z;
    const float* xp = x + ((size_t)b * L_ + (size_t)c * 256) * D_ + j;
    float s = 0.f;
    for (int l = 0; l < 256; ++l) s += xp[(size_t)l * D_];
    atomicAdd(&xmean[b * D_ + j], s * (1.0f / L_));
}

// ---- out[b][j] = dot(in[b], W[j]) + bias[j] ----
__global__ __launch_bounds__(256) void vecmat_kernel(const float* __restrict__ in,
                                                     const float* __restrict__ W,
                                                     const float* __restrict__ bias,
                                                     float* __restrict__ out) {
    __shared__ float vs[D_];
    int b = blockIdx.y;
    int j = blockIdx.x * 256 + threadIdx.x;
    for (int t = threadIdx.x; t < D_; t += 256) vs[t] = in[b * D_ + t];
    __syncthreads();
    const float* wr = W + (size_t)j * D_;
    float acc = 0.f;
    #pragma unroll 4
    for (int k = 0; k < D_; k += 4) {
        float4 w4 = *(const float4*)(wr + k);
        acc += vs[k] * w4.x + vs[k + 1] * w4.y + vs[k + 2] * w4.z + vs[k + 3] * w4.w;
    }
    out[b * D_ + j] = acc + bias[j];
}

// ---- Ksamp (fp32 exact, selection path) ----
__global__ __launch_bounds__(256) void ksamp_kernel(const float* __restrict__ x,
                                                    const float* __restrict__ Wk,
                                                    const float* __restrict__ bk,
                                                    const int* __restrict__ idx_k,
                                                    float* __restrict__ Ksamp, int U) {
    __shared__ float vs[D_];
    int u = blockIdx.x, b = blockIdx.y;
    int row = idx_k[u];
    const float* xp = x + ((size_t)b * L_ + row) * D_;
    for (int t = threadIdx.x; t < D_; t += 256) vs[t] = xp[t];
    __syncthreads();
    #pragma unroll
    for (int r = 0; r < 4; ++r) {
        int j = r * 256 + threadIdx.x;
        const float* wr = Wk + (size_t)j * D_;
        float acc = 0.f;
        #pragma unroll 4
        for (int k = 0; k < D_; k += 4) {
            float4 w4 = *(const float4*)(wr + k);
            acc += vs[k] * w4.x + vs[k + 1] * w4.y + vs[k + 2] * w4.z + vs[k + 3] * w4.w;
        }
        Ksamp[((size_t)b * U + u) * D_ + j] = acc + bk[j];
    }
}

// ---- fused QKV via split-bf16 MFMA ----
#define TM 128
#define TN 128
#define BK 32

__global__ __launch_bounds__(256) void qkv_mfma(
    const unsigned short* __restrict__ xh, const unsigned short* __restrict__ xm,
    const unsigned short* __restrict__ xl,
    const unsigned short* __restrict__ qh, const unsigned short* __restrict__ qm,
    const unsigned short* __restrict__ ql,
    const unsigned short* __restrict__ kh, const unsigned short* __restrict__ km,
    const unsigned short* __restrict__ vh, const unsigned short* __restrict__ vm,
    const float* __restrict__ bq, const float* __restrict__ bk2, const float* __restrict__ bv,
    float* __restrict__ Q, __hip_bfloat16* __restrict__ Kb, __hip_bfloat16* __restrict__ Vb) {
    __shared__ __align__(16) unsigned short As[TM * BK];
    __shared__ __align__(16) unsigned short Bs[TN * BK];

    const int n0 = blockIdx.x * TN;
    const int m0 = blockIdx.y * TM;
    const int tid = threadIdx.x;

    const unsigned short* Ap[6]; const unsigned short* Bp[6]; int P;
    const float* bias; int which; int nb;
    if (n0 < 1024) {
        which = 0; nb = n0; bias = bq; P = 6;
        Ap[0] = xh; Bp[0] = qh; Ap[1] = xh; Bp[1] = qm; Ap[2] = xm; Bp[2] = qh;
        Ap[3] = xh; Bp[3] = ql; Ap[4] = xm; Bp[4] = qm; Ap[5] = xl; Bp[5] = qh;
    } else if (n0 < 2048) {
        which = 1; nb = n0 - 1024; bias = bk2; P = 3;
        Ap[0] = xh; Bp[0] = kh; Ap[1] = xh; Bp[1] = km; Ap[2] = xm; Bp[2] = kh;
    } else {
        which = 2; nb = n0 - 2048; bias = bv; P = 3;
        Ap[0] = xh; Bp[0] = vh; Ap[1] = xh; Bp[1] = vm; Ap[2] = xm; Bp[2] = vh;
    }

    const int srow = tid >> 2;
    const int scol = (tid & 3) * 8;

    const int wave = tid >> 6;
    const int lane = tid & 63;
    const int wm = (wave & 1) * 64;
    const int wn = (wave >> 1) * 64;
    const int fr = lane & 15;
    const int fk = (lane >> 4) * 8;
    const int rbase = (lane >> 4) * 4;

    f32x4 acc[4][4];
    #pragma unroll
    for (int i = 0; i < 4; ++i)
        #pragma unroll
        for (int j = 0; j < 4; ++j)
            acc[i][j] = (f32x4){0.f, 0.f, 0.f, 0.f};

    unsigned short* lA = As + tid * 8;
    unsigned short* lB = Bs + tid * 8;

    for (int p = 0; p < P; ++p) {
        const unsigned short* Aq = Ap[p] + (size_t)m0 * D_;
        const unsigned short* Bq = Bp[p] + (size_t)nb * D_;
        for (int kt = 0; kt < D_; kt += BK) {
            gl2lds16(Aq + (size_t)srow * D_ + kt + scol, lA);
            gl2lds16(Aq + (size_t)(srow + 64) * D_ + kt + scol, lA + 2048);
            gl2lds16(Bq + (size_t)srow * D_ + kt + scol, lB);
            gl2lds16(Bq + (size_t)(srow + 64) * D_ + kt + scol, lB + 2048);
            __syncthreads();
            bf16x8 af[4], bfr[4];
            #pragma unroll
            for (int i = 0; i < 4; ++i) {
                af[i]  = *(const bf16x8*)(As + (wm + i * 16 + fr) * BK + fk);
                bfr[i] = *(const bf16x8*)(Bs + (wn + i * 16 + fr) * BK + fk);
            }
            #pragma unroll
            for (int i = 0; i < 4; ++i)
                #pragma unroll
                for (int j = 0; j < 4; ++j)
                    acc[i][j] = __builtin_amdgcn_mfma_f32_16x16x32_bf16(
                        af[i], bfr[j], acc[i][j], 0, 0, 0);
            __syncthreads();
        }
    }

    float biasv[4];
    #pragma unroll
    for (int j = 0; j < 4; ++j) biasv[j] = bias[nb + wn + j * 16 + fr];

    #pragma unroll
    for (int i = 0; i < 4; ++i) {
        #pragma unroll
        for (int r = 0; r < 4; ++r) {
            size_t row = (size_t)(m0 + wm + i * 16 + rbase + r);
            #pragma unroll
            for (int j = 0; j < 4; ++j) {
                float v = acc[i][j][r] + biasv[j];
                int n = nb + wn + j * 16 + fr;
                if (which == 0)      Q[row * D_ + n] = v;
                else if (which == 1) Kb[row * D_ + n] = __float2bfloat16(v);
                else                 Vb[row * D_ + n] = __float2bfloat16(v);
            }
        }
    }
}

// ---- M[b][h][l] ----
__global__ __launch_bounds__(256) void m_kernel(const float* __restrict__ Q,
                                                const float* __restrict__ Ksamp,
                                                float* __restrict__ M, int U) {
    __shared__ float ks[64 * 64];
    int lc = blockIdx.x, h = blockIdx.y, b = blockIdx.z;
    for (int t = threadIdx.x; t < U * 64; t += 256) {
        int u = t >> 6, d = t & 63;
        ks[t] = Ksamp[((size_t)b * U + u) * D_ + h * 64 + d];
    }
    __syncthreads();
    int l = lc * 256 + threadIdx.x;
    const float* qp = Q + ((size_t)b * L_ + l) * D_ + h * 64;
    float q[64];
    #pragma unroll
    for (int i = 0; i < 16; ++i) *(float4*)&q[i * 4] = *(const float4*)(qp + i * 4);
    float mx = -INFINITY, sm = 0.f;
    for (int u = 0; u < U; ++u) {
        const float* kp = &ks[u * 64];
        float dot = 0.f;
        #pragma unroll
        for (int d = 0; d < 64; ++d) dot = fmaf(q[d], kp[d], dot);
        dot *= SCALE;
        mx = fmaxf(mx, dot);
        sm += dot;
    }
    M[((size_t)(b * H_ + h)) * L_ + l] = mx - sm / (float)U;
}

// ---- top-k via iterative argmax ----
__global__ __launch_bounds__(256) void topk_kernel(const float* __restrict__ M,
                                                   int* __restrict__ topidx, int U) {
    __shared__ float vals[L_];
    __shared__ float rv[256];
    __shared__ int   ri[256];
    int bh = blockIdx.x;
    const float* mp = M + (size_t)bh * L_;
    for (int t = threadIdx.x; t < L_; t += 256) vals[t] = mp[t];
    __syncthreads();
    for (int u = 0; u < U; ++u) {
        float bv = -INFINITY; int bi = 0x7fffffff;
        for (int t = threadIdx.x; t < L_; t += 256) {
            float v = vals[t];
            if (v > bv || (v == bv && t < bi)) { bv = v; bi = t; }
        }
        rv[threadIdx.x] = bv; ri[threadIdx.x] = bi;
        __syncthreads();
        for (int s = 128; s > 0; s >>= 1) {
            if (threadIdx.x < s) {
                float v2 = rv[threadIdx.x + s]; int i2 = ri[threadIdx.x + s];
                if (v2 > rv[threadIdx.x] ||
                    (v2 == rv[threadIdx.x] && i2 < ri[threadIdx.x])) {
                    rv[threadIdx.x] = v2; ri[threadIdx.x] = i2;
                }
            }
            __syncthreads();
        }
        if (threadIdx.x == 0) { topidx[bh * U + u] = ri[0]; vals[ri[0]] = -INFINITY; }
        __syncthreads();
    }
}

// ---- MFMA flash attention: all U queries of one (b,h) share each K/V tile ----
// Block = (chunk c, h, b); 4 waves; wave w owns query rows 16w..16w+15.
// Partials (m, s, acc[64]) per (bh, q, chunk) merged by attn_combine.
__global__ __launch_bounds__(256) void attn_mfma(const float* __restrict__ Q,
        const __hip_bfloat16* __restrict__ Kb, const __hip_bfloat16* __restrict__ Vb,
        const int* __restrict__ topidx,
        float* __restrict__ part_m, float* __restrict__ part_s,
        float* __restrict__ part_acc, int U) {
    __shared__ __align__(16) unsigned short Qh[QPAD * RS];
    __shared__ __align__(16) unsigned short Qm[QPAD * RS];
    __shared__ __align__(16) unsigned short Ks[64 * RS];
    __shared__ __align__(16) unsigned short Vt[64 * RS];   // [dim][key]
    __shared__ __align__(16) unsigned short Ph[QPAD * RS];

    const int c = blockIdx.x, h = blockIdx.y, b = blockIdx.z;
    const int bh = b * H_ + h;
    const int tid = threadIdx.x;
    const int wave = tid >> 6, lane = tid & 63;
    const int w16 = wave * 16;
    const int fr = lane & 15;
    const int quad = lane >> 4;
    const int fk = quad * 8;
    const int l0 = c * (L_ / NC);

    // ---- stage Q rows (gathered via topidx), scale folded, hi/mid split ----
    {
        int u = tid >> 2;
        int d0 = (tid & 3) * 16;
        unsigned short hbuf[16], mbuf[16];
        if (u < U) {
            int row = topidx[bh * U + u];
            const float* qp = Q + ((size_t)b * L_ + row) * D_ + h * 64 + d0;
            #pragma unroll
            for (int i = 0; i < 16; ++i) {
                float v = qp[i] * SCALE;
                unsigned short hb = bfbits(v);
                hbuf[i] = hb;
                mbuf[i] = bfbits(v - bf2f(hb));
            }
        } else {
            #pragma unroll
            for (int i = 0; i < 16; ++i) { hbuf[i] = 0; mbuf[i] = 0; }
        }
        #pragma unroll
        for (int i = 0; i < 2; ++i) {
            *(uint4*)&Qh[u * RS + d0 + i * 8] = ((uint4*)hbuf)[i];
            *(uint4*)&Qm[u * RS + d0 + i * 8] = ((uint4*)mbuf)[i];
        }
    }

    float m_r[4], s_r[4];
    f32x4 acc_o[4];
    #pragma unroll
    for (int r = 0; r < 4; ++r) { m_r[r] = -INFINITY; s_r[r] = 0.f; }
    #pragma unroll
    for (int n = 0; n < 4; ++n) acc_o[n] = (f32x4){0.f, 0.f, 0.f, 0.f};

    __syncthreads();

    for (int kt = 0; kt < L_ / NC; kt += 64) {
        // ---- stage K tile [key][dim] ----
        {
            int key = tid >> 3;
            int d0 = (tid & 7) * 8;
            const __hip_bfloat16* kp = Kb + ((size_t)b * L_ + l0 + kt) * D_ + h * 64;
            *(uint4*)&Ks[key * RS + d0] = *(const uint4*)(kp + (size_t)key * D_ + d0);
            *(uint4*)&Ks[(key + 32) * RS + d0] =
                *(const uint4*)(kp + (size_t)(key + 32) * D_ + d0);
        }
        // ---- stage V tile transposed -> Vt[dim][key] ----
        {
            int key = tid & 63;
            int g = tid >> 6;
            const __hip_bfloat16* vp = Vb + ((size_t)b * L_ + l0 + kt + key) * D_ + h * 64;
            #pragma unroll
            for (int rr = 0; rr < 2; ++rr) {
                int d0 = rr * 32 + g * 8;
                ushort4 v0 = *(const ushort4*)(vp + d0);
                ushort4 v1 = *(const ushort4*)(vp + d0 + 4);
                Vt[(d0 + 0) * RS + key] = v0.x;
                Vt[(d0 + 1) * RS + key] = v0.y;
                Vt[(d0 + 2) * RS + key] = v0.z;
                Vt[(d0 + 3) * RS + key] = v0.w;
                Vt[(d0 + 4) * RS + key] = v1.x;
                Vt[(d0 + 5) * RS + key] = v1.y;
                Vt[(d0 + 6) * RS + key] = v1.z;
                Vt[(d0 + 7) * RS + key] = v1.w;
            }
        }
        __syncthreads();

        // ---- S = Q·K^T (split-2) ----
        f32x4 sacc[4];
        #pragma unroll
        for (int n = 0; n < 4; ++n) {
            sacc[n] = (f32x4){0.f, 0.f, 0.f, 0.f};
            #pragma unroll
            for (int ks = 0; ks < 2; ++ks) {
                int k0 = ks * 32;
                bf16x8 ah = *(const bf16x8*)&Qh[(w16 + fr) * RS + k0 + fk];
                bf16x8 am = *(const bf16x8*)&Qm[(w16 + fr) * RS + k0 + fk];
                bf16x8 bb = *(const bf16x8*)&Ks[(n * 16 + fr) * RS + k0 + fk];
                sacc[n] = __builtin_amdgcn_mfma_f32_16x16x32_bf16(ah, bb, sacc[n], 0, 0, 0);
                sacc[n] = __builtin_amdgcn_mfma_f32_16x16x32_bf16(am, bb, sacc[n], 0, 0, 0);
            }
        }

        // ---- online softmax per query row ----
        float p[4][4];
        #pragma unroll
        for (int r = 0; r < 4; ++r) {
            float rowmax = fmaxf(fmaxf(sacc[0][r], sacc[1][r]),
                                 fmaxf(sacc[2][r], sacc[3][r]));
            #pragma unroll
            for (int msk = 1; msk <= 8; msk <<= 1)
                rowmax = fmaxf(rowmax, __shfl_xor(rowmax, msk, 64));
            float mnew = fmaxf(m_r[r], rowmax);
            float alpha = __expf(m_r[r] - mnew);
            float rowsum = 0.f;
            #pragma unroll
            for (int n = 0; n < 4; ++n) {
                p[n][r] = __expf(sacc[n][r] - mnew);
                rowsum += p[n][r];
            }
            #pragma unroll
            for (int msk = 1; msk <= 8; msk <<= 1)
                rowsum += __shfl_xor(rowsum, msk, 64);
            s_r[r] = s_r[r] * alpha + rowsum;
            m_r[r] = mnew;
            #pragma unroll
            for (int n = 0; n < 4; ++n) acc_o[n][r] *= alpha;
        }

        // ---- P (C-layout) -> Ph (A-layout) via per-wave-private LDS strip ----
        #pragma unroll
        for (int r = 0; r < 4; ++r)
            #pragma unroll
            for (int n = 0; n < 4; ++n)
                Ph[(w16 + quad * 4 + r) * RS + n * 16 + fr] = bfbits(p[n][r]);

        // ---- O += P·V ----
        #pragma unroll
        for (int n = 0; n < 4; ++n) {
            #pragma unroll
            for (int ks = 0; ks < 2; ++ks) {
                int k0 = ks * 32;
                bf16x8 pa = *(const bf16x8*)&Ph[(w16 + fr) * RS + k0 + fk];
                bf16x8 vb = *(const bf16x8*)&Vt[(n * 16 + fr) * RS + k0 + fk];
                acc_o[n] = __builtin_amdgcn_mfma_f32_16x16x32_bf16(pa, vb, acc_o[n], 0, 0, 0);
            }
        }
        __syncthreads();
    }

    // ---- write partials ----
    #pragma unroll
    for (int r = 0; r < 4; ++r) {
        int q = w16 + quad * 4 + r;
        if (q < U) {
            size_t base = ((size_t)(bh * QPAD + q)) * NC + c;
            if (fr == 0) { part_m[base] = m_r[r]; part_s[base] = s_r[r]; }
            #pragma unroll
            for (int n = 0; n < 4; ++n)
                part_acc[base * 64 + n * 16 + fr] = acc_o[n][r];
        }
    }
}

// ---- merge NC chunk partials -> ctx_top ----
__global__ __launch_bounds__(64) void attn_combine(const float* __restrict__ part_m,
        const float* __restrict__ part_s, const float* __restrict__ part_acc,
        float* __restrict__ ctx_top, int U) {
    int u = blockIdx.x, h = blockIdx.y, b = blockIdx.z;
    int bh = b * H_ + h;
    int d = threadIdx.x;
    size_t base = ((size_t)(bh * QPAD + u)) * NC;
    float M = -INFINITY;
    #pragma unroll
    for (int c = 0; c < NC; ++c) M = fmaxf(M, part_m[base + c]);
    float S = 0.f, A = 0.f;
    #pragma unroll
    for (int c = 0; c < NC; ++c) {
        float f = __expf(part_m[base + c] - M);
        S += part_s[base + c] * f;
        A += part_acc[(base + c) * 64 + d] * f;
    }
    ctx_top[(((size_t)bh) * U + u) * 64 + d] = A / S;
}

// ---- out[b][l][:] = base[b][:] ----
__global__ __launch_bounds__(256) void fill_base_kernel(const float* __restrict__ base,
                                                        float* __restrict__ out) {
    size_t i = (size_t)blockIdx.x * 256 + threadIdx.x;
    int col4 = (int)(i & 255);
    int b = (int)(i >> 21);
    ((float4*)out)[i] = ((const float4*)base)[b * 256 + col4];
}

// ---- out[b][row][:] += (ctx_top - vmean_h) @ Wo_h.T ----
__global__ __launch_bounds__(256) void delta_kernel(const float* __restrict__ ctx_top,
        const float* __restrict__ vmean, const float* __restrict__ Wo,
        const int* __restrict__ topidx, float* __restrict__ out, int U) {
    __shared__ float cd[64];
    int u = blockIdx.x, h = blockIdx.y, b = blockIdx.z;
    int row = topidx[(b * H_ + h) * U + u];
    if (threadIdx.x < 64) {
        cd[threadIdx.x] = ctx_top[(((size_t)(b * H_ + h)) * U + u) * 64 + threadIdx.x]
                        - vmean[b * D_ + h * 64 + threadIdx.x];
    }
    __syncthreads();
    float* op = out + ((size_t)b * L_ + row) * D_;
    #pragma unroll
    for (int r = 0; r < 4; ++r) {
        int j = r * 256 + threadIdx.x;
        const float* wr = Wo + (size_t)j * D_ + h * 64;
        float dlt = 0.f;
        #pragma unroll
        for (int k = 0; k < 64; k += 4) {
            float4 w4 = *(const float4*)(wr + k);
            dlt += cd[k] * w4.x + cd[k + 1] * w4.y + cd[k + 2] * w4.z + cd[k + 3] * w4.w;
        }
        atomicAdd(op + j, dlt);
    }
}

extern "C" void kernel_launch(void* const* d_in, const int* in_sizes, int n_in,
                              void* d_out, int out_size, void* d_ws, size_t ws_size,
                              hipStream_t stream) {
    const float* x   = (const float*)d_in[0];
    const float* Wq  = (const float*)d_in[1];
    const float* bq  = (const float*)d_in[2];
    const float* Wk  = (const float*)d_in[3];
    const float* bk  = (const float*)d_in[4];
    const float* Wv  = (const float*)d_in[5];
    const float* bv  = (const float*)d_in[6];
    const float* Wo  = (const float*)d_in[7];
    const float* bo  = (const float*)d_in[8];
    const int* idx_k = (const int*)d_in[9];
    const int U = in_sizes[9];
    float* out = (float*)d_out;
    (void)n_in; (void)ws_size;

    char* ws = (char*)d_ws;
    size_t off = 0;
    auto alloc = [&](size_t bytes) -> void* {
        void* p = ws + off;
        off += (bytes + 255) & ~(size_t)255;
        return p;
    };
    float* Q              = (float*)alloc((size_t)B_ * L_ * D_ * 4);
    __hip_bfloat16* Kb    = (__hip_bfloat16*)alloc((size_t)B_ * L_ * D_ * 2);
    __hip_bfloat16* Vb    = (__hip_bfloat16*)alloc((size_t)B_ * L_ * D_ * 2);
    unsigned short* xh    = (unsigned short*)alloc((size_t)B_ * L_ * D_ * 2);
    unsigned short* xm    = (unsigned short*)alloc((size_t)B_ * L_ * D_ * 2);
    unsigned short* xl    = (unsigned short*)alloc((size_t)B_ * L_ * D_ * 2);
    unsigned short* wqh   = (unsigned short*)alloc((size_t)D_ * D_ * 2);
    unsigned short* wqm   = (unsigned short*)alloc((size_t)D_ * D_ * 2);
    unsigned short* wql   = (unsigned short*)alloc((size_t)D_ * D_ * 2);
    unsigned short* wkh   = (unsigned short*)alloc((size_t)D_ * D_ * 2);
    unsigned short* wkm   = (unsigned short*)alloc((size_t)D_ * D_ * 2);
    unsigned short* wvh   = (unsigned short*)alloc((size_t)D_ * D_ * 2);
    unsigned short* wvm   = (unsigned short*)alloc((size_t)D_ * D_ * 2);
    float* Ksamp          = (float*)alloc((size_t)B_ * 64 * D_ * 4);
    float* Mbuf           = (float*)alloc((size_t)B_ * H_ * L_ * 4);
    int*   topidx         = (int*)alloc((size_t)B_ * H_ * 64 * 4);
    float* xmean          = (float*)alloc((size_t)B_ * D_ * 4);
    float* vmean          = (float*)alloc((size_t)B_ * D_ * 4);
    float* base           = (float*)alloc((size_t)B_ * D_ * 4);
    float* ctxt           = (float*)alloc((size_t)B_ * H_ * 64 * 64 * 4);
    float* part_m         = (float*)alloc((size_t)B_ * H_ * QPAD * NC * 4);
    float* part_s         = (float*)alloc((size_t)B_ * H_ * QPAD * NC * 4);
    float* part_acc       = (float*)alloc((size_t)B_ * H_ * QPAD * NC * 64 * 4);

    hipMemsetAsync(xmean, 0, (size_t)B_ * D_ * 4, stream);
    xmean_kernel<<<dim3(32, 4, B_), 256, 0, stream>>>(x, xmean);
    vecmat_kernel<<<dim3(4, B_), 256, 0, stream>>>(xmean, Wv, bv, vmean);
    vecmat_kernel<<<dim3(4, B_), 256, 0, stream>>>(vmean, Wo, bo, base);
    ksamp_kernel<<<dim3(U, B_), 256, 0, stream>>>(x, Wk, bk, idx_k, Ksamp, U);

    const int n4x = B_ * L_ * D_ / 4;
    const int n4w = D_ * D_ / 4;
    split3_kernel<<<dim3(n4x / 256), 256, 0, stream>>>(x, xh, xm, xl, n4x);
    split3_kernel<<<dim3(n4w / 256), 256, 0, stream>>>(Wq, wqh, wqm, wql, n4w);
    split2_kernel<<<dim3(n4w / 256), 256, 0, stream>>>(Wk, wkh, wkm, n4w);
    split2_kernel<<<dim3(n4w / 256), 256, 0, stream>>>(Wv, wvh, wvm, n4w);

    qkv_mfma<<<dim3(24, 256), 256, 0, stream>>>(xh, xm, xl, wqh, wqm, wql,
                                                wkh, wkm, wvh, wvm,
                                                bq, bk, bv, Q, Kb, Vb);

    m_kernel<<<dim3(32, H_, B_), 256, 0, stream>>>(Q, Ksamp, Mbuf, U);
    topk_kernel<<<dim3(B_ * H_), 256, 0, stream>>>(Mbuf, topidx, U);
    attn_mfma<<<dim3(NC, H_, B_), 256, 0, stream>>>(Q, Kb, Vb, topidx,
                                                    part_m, part_s, part_acc, U);
    attn_combine<<<dim3(U, H_, B_), 64, 0, stream>>>(part_m, part_s, part_acc, ctxt, U);
    fill_base_kernel<<<dim3(out_size / 4 / 256), 256, 0, stream>>>(base, out);
    delta_kernel<<<dim3(U, H_, B_), 256, 0, stream>>>(ctxt, vmean, Wo, topidx, out, U);
}